// Round 8
// baseline (116.624 us; speedup 1.0000x reference)
//
#include <hip/hip_runtime.h>

// Problem constants
#define B_    4
#define CIN_  64
#define COUT_ 64
#define H_    128
#define W_    128
#define HW_   (H_*W_)
#define K2_   9
#define NOFF_ 18

// padded NHWC fp16 tensor: rows -2..129 (132), cols -3..132 (136), 64 ch
#define PR_   132
#define PC_   136
// x tile in LDS: rows oh-2..oh+2, cols ow0-3..ow0+66
// swizzled layout: 16B seg index d = (row*8 + slot)*TCOLS + col, slot = ch>>3
//   read bank residue = (6*slot + col) % 8, col varies per lane -> uniform
// staged with LINEAR lds dest + pre-swizzled global source (global_load_lds)
#define TROWS 5
#define TCOLS 70
#define NSEG  (TROWS * 8 * TCOLS)        // 2800 16B segments
#define NSEGP 2816                       // padded to 11*256 (pad never read)

typedef _Float16 f16x8 __attribute__((ext_vector_type(8)));  // MFMA A/B frag
typedef float    f32x4 __attribute__((ext_vector_type(4)));  // MFMA C/D

__device__ __forceinline__ f16x8 splat8(float f) {
    _Float16 h = (_Float16)f;
    return (f16x8){h, h, h, h, h, h, h, h};
}
__device__ __forceinline__ f16x8 splat8h(_Float16 h) {
    return (f16x8){h, h, h, h, h, h, h, h};
}
__device__ __forceinline__ _Float16 lo16(unsigned u) {
    return __builtin_bit_cast(_Float16, (unsigned short)(u & 0xffffu));
}
__device__ __forceinline__ _Float16 hi16(unsigned u) {
    return __builtin_bit_cast(_Float16, (unsigned short)(u >> 16));
}

// ---------------------------------------------------------------------------
// x (NCHW fp32) -> hx interior (padded NHWC fp16), fused with:
//   - DENSE fp16 weight repack: one MFMA A-frag = one contiguous 1KB block
//       wt_b [((mb*9+k2)*2+kb)*512 + nl*32 + cc] = wd[o=mb*16+nl][c=kb*32+cc][k2]
//       wt_ob same with mt in 0..1 (rows 18..31 zero)
//   - border-only zero of hx (interior fully overwritten here)
// Block = (b, y) row; thread = (xpos, c-half). 512 blocks x 256 thr.
// ---------------------------------------------------------------------------
#define NW_B   (COUT_ * 576)                 // 36864 wt_b halfs
#define NW_OB  (32 * 576)                    // 18432 wt_ob halfs
#define NBORD  (4 * 12544)                   // 50176 border 16B segments
__global__ __launch_bounds__(256) void x2h_prep(const float* __restrict__ x,
                                                const float* __restrict__ wd,
                                                const float* __restrict__ wo,
                                                _Float16* __restrict__ hx,
                                                _Float16* __restrict__ wt_b,
                                                _Float16* __restrict__ wt_ob) {
    const int blk = blockIdx.x;          // b*128 + y
    const int b = blk >> 7, y = blk & 127;
    const int xp = threadIdx.x & 127;
    const int ch = threadIdx.x >> 7;     // 0/1 -> channels 0-31 / 32-63
    const float* xs = x + ((b * CIN_ + ch * 32) * H_ + y) * W_ + xp;
    _Float16* hd = hx + (((size_t)b * PR_ + y + 2) * PC_ + xp + 3) * 64 + ch * 32;

    f16x8 h[4];
    #pragma unroll
    for (int j = 0; j < 4; ++j)
        #pragma unroll
        for (int t = 0; t < 8; ++t)
            h[j][t] = (_Float16)xs[(j * 8 + t) * HW_];
    #pragma unroll
    for (int j = 0; j < 4; ++j)
        *(f16x8*)(hd + j * 8) = h[j];

    // ---- side tasks: weight repack + border zeroing (one task per thread) --
    const int gid = blk * 256 + threadIdx.x;
    if (gid < NW_B) {
        int blk512 = gid >> 9, w = gid & 511;
        int nl = w >> 5, cc = w & 31;
        int kb = blk512 & 1, t = blk512 >> 1;
        int mb = t / 9, k2 = t - 9 * mb;
        int o = mb * 16 + nl, c = kb * 32 + cc;
        wt_b[gid] = (_Float16)wd[(o * CIN_ + c) * K2_ + k2];
    } else if (gid < NW_B + NW_OB) {
        int u = gid - NW_B;
        int blk512 = u >> 9, w = u & 511;
        int nl = w >> 5, cc = w & 31;
        int kb = blk512 & 1, t = blk512 >> 1;
        int mt = t / 9, k2 = t - 9 * mt;
        int oc = mt * 16 + nl, c = kb * 32 + cc;
        wt_ob[u] = (_Float16)((oc < NOFF_) ? wo[(oc * CIN_ + c) * K2_ + k2] : 0.f);
    } else if (gid < NW_B + NW_OB + NBORD) {
        int s = gid - (NW_B + NW_OB);
        int b2 = s / 12544, u = s % 12544;
        int cs = u & 7, cell = u >> 3;   // 1568 border cells per image
        int r, c;
        if (cell < 544) {                // padded rows {0,1,130,131}, all cols
            int r4 = cell / 136; c = cell % 136;
            r = (r4 < 2) ? r4 : r4 + 128;
        } else {                         // rows 2..129, cols {0,1,2,131..135}
            int c2 = cell - 544;
            r = 2 + (c2 >> 3);
            int c8 = c2 & 7;
            c = (c8 < 3) ? c8 : c8 + 128;
        }
        *(f16x8*)(hx + (((size_t)b2 * PR_ + r) * PC_ + c) * 64 + cs * 8) = splat8(0.f);
    }
}

// ---------------------------------------------------------------------------
// Fused, LATE-BARRIER: issue DMA-stage of hx tile -> offset conv with B-frags
// read DIRECTLY from L2-resident hx (independent of the staging!) -> offsets
// to regs via shfl -> precomputed metadata -> __syncthreads (staging long
// done) -> main loop {A-frag loads -> 8 straight-line clamped LDS corner
// loads -> blend -> rare fixup-overwrite -> 8 MFMA (setprio)}.
// The barrier's vmcnt-drain is covered by ~2500 cy of independent compute.
// Block = 64 px, 256 thr (4 waves), ONE barrier, 44 KiB LDS -> 3 blocks/CU.
// ---------------------------------------------------------------------------
__global__ __launch_bounds__(256, 3) void deform_all(const _Float16* __restrict__ hx,
                                                     const _Float16* __restrict__ wt_b,
                                                     const _Float16* __restrict__ wt_ob,
                                                     float* __restrict__ out) {
    __shared__ __align__(16) _Float16 xt[NSEGP * 8];   // 44 KiB

    const int tid = threadIdx.x;
    int blk = blockIdx.x;
    blk = (blk & 7) * 128 + (blk >> 3);    // XCD swizzle (1024 % 8 == 0, bijective)
    const int b   = blk >> 8;
    const int r2  = blk & 255;
    const int oh  = r2 >> 1;
    const int ow0 = (r2 & 1) << 6;

    // ---- issue tile staging: global_load_lds, linear dest, swizzled src ----
    // NOT waited on here — consumed only after the late __syncthreads below.
    const _Float16* hrow = hx + (((size_t)b * PR_ + oh) * PC_ + ow0) * 64;
    #pragma unroll
    for (int t = 0; t < NSEGP / 256; ++t) {
        int d  = t * 256 + tid;            // linear LDS 16B-seg index
        int dc = min(d, NSEG - 1);         // clamp pad lanes to a valid src
        int col = dc % TCOLS;
        int rc  = dc / TCOLS;
        int cs  = rc & 7;                  // channel octet (slot)
        int r   = rc >> 3;                 // tile row
        const _Float16* src = hrow + ((size_t)r * PC_ + col) * 64 + cs * 8;
        __builtin_amdgcn_global_load_lds(
            (const __attribute__((address_space(1))) void*)src,
            (__attribute__((address_space(3))) void*)(xt + (size_t)d * 8),
            16, 0, 0);
    }

    const int lane = tid & 63;
    const int cq   = tid >> 6;             // wave id -> pixel group
    const int quad = lane >> 4;            // channel octet within kb half
    const int nl   = lane & 15;
    const int pix  = cq * 16 + nl;         // this lane's pixel (B-frag column)
    const int ow   = ow0 + pix;

    const _Float16* wob_l = wt_ob + nl * 32 + quad * 8;   // dense frag base
    const _Float16* wtb_l = wt_b  + nl * 32 + quad * 8;
    const _Float16* hb    = hx + (size_t)b * (PR_ * PC_ * 64);

    // ---- offset conv via f16 MFMA, B-frags DIRECT from hx (L2-resident) ----
    // lane(nl,quad) addr = base + nl*128B + quad*16B -> 16 full 64B lines/instr
    // (independent of the in-flight LDS staging; hides its latency)
    f32x4 oacc[2];
    oacc[0] = (f32x4){0.f, 0.f, 0.f, 0.f};
    oacc[1] = (f32x4){0.f, 0.f, 0.f, 0.f};
    #pragma unroll
    for (int t9 = 0; t9 < 9; ++t9) {
        int ky = t9 / 3, kx = t9 - 3 * (t9 / 3);
        #pragma unroll
        for (int kb = 0; kb < 2; ++kb) {
            f16x8 bfr = *(const f16x8*)(hb + (((oh + ky + 1) * PC_) + (ow + kx + 2)) * 64
                                           + kb * 32 + quad * 8);
            #pragma unroll
            for (int mt = 0; mt < 2; ++mt) {
                f16x8 afr = *(const f16x8*)(wob_l + (((mt * 9 + t9) * 2 + kb) << 9));
                oacc[mt] = __builtin_amdgcn_mfma_f32_16x16x32_f16(afr, bfr, oacc[mt], 0, 0, 0);
            }
        }
    }
    // oacc[mt][r] holds offset-channel oc = mt*16 + quad*4 + r for pixel cq*16+nl.

    // ---- hoist ALL offsets for this lane's pixel into registers (18 shfl) ----
    float dyv[9], dxv[9];
    #pragma unroll
    for (int k2 = 0; k2 < 9; ++k2) {
        const int oc0 = 2 * k2;
        const int mt  = oc0 >> 4;
        const int sq  = (oc0 & 15) >> 2;
        const int r0  = oc0 & 3;
        dyv[k2] = __shfl(oacc[mt][r0],     sq * 16 + nl, 64);
        dxv[k2] = __shfl(oacc[mt][r0 + 1], sq * 16 + nl, 64);
    }

    // ---- precompute ALL sampling metadata (9-way ILP, off critical path) ----
    int      A00[9];
    unsigned Wp[9][2];            // [0]=w00|w01<<16, [1]=w10|w11<<16 (f16 bits)
    int      P0[9];               // (y0 & 0xffff) | (x0 << 16)
    unsigned okm = 0, dxm = 0, dym = 0;
    #pragma unroll
    for (int k2 = 0; k2 < 9; ++k2) {
        const int ky = k2 / 3, kx = k2 - 3 * (k2 / 3);
        float py = (float)(oh - 1 + ky) + dyv[k2];
        float px = (float)(ow - 1 + kx) + dxv[k2];
        float y0f = floorf(py), x0f = floorf(px);
        float ly = py - y0f,    lx = px - x0f;
        int   y0 = (int)y0f,    x0 = (int)x0f;
        int   y1 = y0 + 1,      x1 = x0 + 1;

        float wy0 = 1.f - ly, wx0 = 1.f - lx;
        float w00 = wy0 * wx0, w01 = wy0 * lx, w10 = ly * wx0, w11 = ly * lx;

        bool vy0 = (unsigned)y0 < (unsigned)H_;
        bool vy1 = (unsigned)y1 < (unsigned)H_;
        bool vx0 = (unsigned)x0 < (unsigned)W_;
        bool vx1 = (unsigned)x1 < (unsigned)W_;
        if (!(vy0 & vx0)) w00 = 0.f;
        if (!(vy0 & vx1)) w01 = 0.f;
        if (!(vy1 & vx0)) w10 = 0.f;
        if (!(vy1 & vx1)) w11 = 0.f;
        unsigned h00 = (unsigned)__builtin_bit_cast(unsigned short, (_Float16)w00);
        unsigned h01 = (unsigned)__builtin_bit_cast(unsigned short, (_Float16)w01);
        unsigned h10 = (unsigned)__builtin_bit_cast(unsigned short, (_Float16)w10);
        unsigned h11 = (unsigned)__builtin_bit_cast(unsigned short, (_Float16)w11);
        Wp[k2][0] = h00 | (h01 << 16);
        Wp[k2][1] = h10 | (h11 << 16);
        P0[k2] = (y0 & 0xffff) | (x0 << 16);

        int ty0 = y0 - (oh - 2), ty1 = ty0 + 1;
        int tx0 = x0 - (ow0 - 3), tx1 = tx0 + 1;
        bool i00 = (unsigned)ty0 < TROWS && (unsigned)tx0 < TCOLS;
        bool i01 = (unsigned)ty0 < TROWS && (unsigned)tx1 < TCOLS;
        bool i10 = (unsigned)ty1 < TROWS && (unsigned)tx0 < TCOLS;
        bool i11 = (unsigned)ty1 < TROWS && (unsigned)tx1 < TCOLS;
        bool ok = (w00 == 0.f || i00) && (w01 == 0.f || i01) &&
                  (w10 == 0.f || i10) && (w11 == 0.f || i11);
        if (ok) okm |= 1u << k2;

        int tyc0 = min(max(ty0, 0), TROWS - 1), tyc1 = min(max(ty1, 0), TROWS - 1);
        int txc0 = min(max(tx0, 0), TCOLS - 1), txc1 = min(max(tx1, 0), TCOLS - 1);
        if (txc1 != txc0) dxm |= 1u << k2;     // => txc1 == txc0 + 1
        if (tyc1 != tyc0) dym |= 1u << k2;     // => tyc1 == tyc0 + 1
        A00[k2] = ((tyc0 * 8 + quad) * TCOLS + txc0) * 8;
    }

    __syncthreads();   // late barrier: staging long complete under oconv+meta

    // ---- main loop: straight-line loads, rare fixup, MFMA ------------------
    f32x4 acc[4];
    #pragma unroll
    for (int mb = 0; mb < 4; ++mb) acc[mb] = (f32x4){0.f, 0.f, 0.f, 0.f};

    const int KB1 = 4 * TCOLS * 8;             // slot +4 => channels +32

    #pragma unroll
    for (int k2 = 0; k2 < 9; ++k2) {
        // A-frag VMEM loads for THIS k2 (early issue; consumed after blend)
        f16x8 af0[4], af1[4];
        #pragma unroll
        for (int mb = 0; mb < 4; ++mb) {
            af0[mb] = *(const f16x8*)(wtb_l + (((mb * 9 + k2) * 2 + 0) << 9));
            af1[mb] = *(const f16x8*)(wtb_l + (((mb * 9 + k2) * 2 + 1) << 9));
        }

        // unconditional clamped corner loads (always in-tile addresses)
        const int a00 = A00[k2];
        const int a01 = a00 + (int)((dxm >> k2) & 1u) * 8;
        const int a10 = a00 + (int)((dym >> k2) & 1u) * (8 * TCOLS * 8);
        const int a11 = a10 + (a01 - a00);
        f16x8 c00a = *(const f16x8*)&xt[a00], c00b = *(const f16x8*)&xt[a00 + KB1];
        f16x8 c01a = *(const f16x8*)&xt[a01], c01b = *(const f16x8*)&xt[a01 + KB1];
        f16x8 c10a = *(const f16x8*)&xt[a10], c10b = *(const f16x8*)&xt[a10 + KB1];
        f16x8 c11a = *(const f16x8*)&xt[a11], c11b = *(const f16x8*)&xt[a11 + KB1];

        f16x8 W00 = splat8h(lo16(Wp[k2][0])), W01 = splat8h(hi16(Wp[k2][0]));
        f16x8 W10 = splat8h(lo16(Wp[k2][1])), W11 = splat8h(hi16(Wp[k2][1]));

        // clamped blend (correct whenever ok; overwritten by rare fixup else)
        f16x8 v0 = c00a * W00 + c01a * W01 + c10a * W10 + c11a * W11;
        f16x8 v1 = c00b * W00 + c01b * W01 + c10b * W10 + c11b * W11;

        if (!((okm >> k2) & 1u)) {
            // rare fixup: image-clamped gather from padded hx (overwrites v0/v1)
            int pk = P0[k2];
            int y0 = (pk << 16) >> 16;          // sext low16
            int x0 = pk >> 16;
            int y0c = min(max(y0, 0), H_ - 1), y1c = min(max(y0 + 1, 0), H_ - 1);
            int x0c = min(max(x0, 0), W_ - 1), x1c = min(max(x0 + 1, 0), W_ - 1);
            const _Float16* hg = hb + quad * 8;
            const _Float16* g00 = hg + (((y0c + 2) * PC_) + x0c + 3) * 64;
            const _Float16* g01 = hg + (((y0c + 2) * PC_) + x1c + 3) * 64;
            const _Float16* g10 = hg + (((y1c + 2) * PC_) + x0c + 3) * 64;
            const _Float16* g11 = hg + (((y1c + 2) * PC_) + x1c + 3) * 64;
            v0 = (*(const f16x8*)g00) * W00 + (*(const f16x8*)g01) * W01 +
                 (*(const f16x8*)g10) * W10 + (*(const f16x8*)g11) * W11;
            v1 = (*(const f16x8*)(g00 + 32)) * W00 + (*(const f16x8*)(g01 + 32)) * W01 +
                 (*(const f16x8*)(g10 + 32)) * W10 + (*(const f16x8*)(g11 + 32)) * W11;
        }

        __builtin_amdgcn_s_setprio(1);
        #pragma unroll
        for (int mb = 0; mb < 4; ++mb) {
            acc[mb] = __builtin_amdgcn_mfma_f32_16x16x32_f16(af0[mb], v0, acc[mb], 0, 0, 0);
            acc[mb] = __builtin_amdgcn_mfma_f32_16x16x32_f16(af1[mb], v1, acc[mb], 0, 0, 0);
        }
        __builtin_amdgcn_s_setprio(0);
    }

    // epilogue: C/D col = pixel (nl), row = quad*4 + r (verified layout)
    #pragma unroll
    for (int mb = 0; mb < 4; ++mb)
        #pragma unroll
        for (int r = 0; r < 4; ++r) {
            int o = mb * 16 + quad * 4 + r;
            out[(b * COUT_ + o) * HW_ + oh * W_ + ow0 + pix] = acc[mb][r];
        }
}

// ---------------------------------------------------------------------------
extern "C" void kernel_launch(void* const* d_in, const int* in_sizes, int n_in,
                              void* d_out, int out_size, void* d_ws, size_t ws_size,
                              hipStream_t stream) {
    const float* x        = (const float*)d_in[0];  // (4, 64, 128, 128)
    const float* w_offset = (const float*)d_in[1];  // (18, 64, 3, 3)
    const float* w_deform = (const float*)d_in[2];  // (64, 64, 3, 3)
    float* out = (float*)d_out;                     // (4, 64, 128, 128)

    _Float16* hx    = (_Float16*)d_ws;                        // 4*132*136*64 halfs (9.2 MB)
    _Float16* wt_b  = hx + (size_t)B_ * PR_ * PC_ * 64;       // 36864 halfs (dense frags)
    _Float16* wt_ob = wt_b + (size_t)NW_B;                    // 18432 halfs (dense frags)

    x2h_prep<<<B_ * H_, 256, 0, stream>>>(x, w_deform, w_offset, hx, wt_b, wt_ob);
    deform_all<<<B_ * H_ * (W_ / 64), 256, 0, stream>>>(hx, wt_b, wt_ob, out);
}

// Round 9
// 110.497 us; speedup vs baseline: 1.0555x; 1.0555x over previous
//
#include <hip/hip_runtime.h>

// Problem constants
#define B_    4
#define CIN_  64
#define COUT_ 64
#define H_    128
#define W_    128
#define HW_   (H_*W_)
#define K2_   9
#define NOFF_ 18

// padded NHWC fp16 tensor: rows -2..129 (132), cols -3..132 (136), 64 ch
#define PR_   132
#define PC_   136
// x tile in LDS: rows oh-2..oh+2, cols ow0-3..ow0+66
// swizzled layout: 16B seg index d = (row*8 + slot)*TCOLS + col, slot = ch>>3
//   read bank residue = (6*slot + col) % 8, col varies per lane -> uniform
// staged with LINEAR lds dest + pre-swizzled global source (global_load_lds)
#define TROWS 5
#define TCOLS 70
#define NSEG  (TROWS * 8 * TCOLS)        // 2800 16B segments
#define NSEGP 2816                       // padded to 11*256 (pad never read)

typedef _Float16 f16x8 __attribute__((ext_vector_type(8)));  // MFMA A/B frag
typedef float    f32x4 __attribute__((ext_vector_type(4)));  // MFMA C/D

__device__ __forceinline__ f16x8 splat8(float f) {
    _Float16 h = (_Float16)f;
    return (f16x8){h, h, h, h, h, h, h, h};
}

// ---------------------------------------------------------------------------
// x (NCHW fp32) -> hx interior (padded NHWC fp16), fused with:
//   - DENSE fp16 weight repack: one MFMA A-frag = one contiguous 1KB block
//       wt_b [((mb*9+k2)*2+kb)*512 + nl*32 + cc] = wd[o=mb*16+nl][c=kb*32+cc][k2]
//       wt_ob same with mt in 0..1 (rows 18..31 zero)
//   - border-only zero of hx (interior fully overwritten here)
// Block = (b, y) row; thread = (xpos, c-half). 512 blocks x 256 thr.
// ---------------------------------------------------------------------------
#define NW_B   (COUT_ * 576)                 // 36864 wt_b halfs
#define NW_OB  (32 * 576)                    // 18432 wt_ob halfs
#define NBORD  (4 * 12544)                   // 50176 border 16B segments
__global__ __launch_bounds__(256) void x2h_prep(const float* __restrict__ x,
                                                const float* __restrict__ wd,
                                                const float* __restrict__ wo,
                                                _Float16* __restrict__ hx,
                                                _Float16* __restrict__ wt_b,
                                                _Float16* __restrict__ wt_ob) {
    const int blk = blockIdx.x;          // b*128 + y
    const int b = blk >> 7, y = blk & 127;
    const int xp = threadIdx.x & 127;
    const int ch = threadIdx.x >> 7;     // 0/1 -> channels 0-31 / 32-63
    const float* xs = x + ((b * CIN_ + ch * 32) * H_ + y) * W_ + xp;
    _Float16* hd = hx + (((size_t)b * PR_ + y + 2) * PC_ + xp + 3) * 64 + ch * 32;

    f16x8 h[4];
    #pragma unroll
    for (int j = 0; j < 4; ++j)
        #pragma unroll
        for (int t = 0; t < 8; ++t)
            h[j][t] = (_Float16)xs[(j * 8 + t) * HW_];
    #pragma unroll
    for (int j = 0; j < 4; ++j)
        *(f16x8*)(hd + j * 8) = h[j];

    // ---- side tasks: weight repack + border zeroing (one task per thread) --
    const int gid = blk * 256 + threadIdx.x;
    if (gid < NW_B) {
        int blk512 = gid >> 9, w = gid & 511;
        int nl = w >> 5, cc = w & 31;
        int kb = blk512 & 1, t = blk512 >> 1;
        int mb = t / 9, k2 = t - 9 * mb;
        int o = mb * 16 + nl, c = kb * 32 + cc;
        wt_b[gid] = (_Float16)wd[(o * CIN_ + c) * K2_ + k2];
    } else if (gid < NW_B + NW_OB) {
        int u = gid - NW_B;
        int blk512 = u >> 9, w = u & 511;
        int nl = w >> 5, cc = w & 31;
        int kb = blk512 & 1, t = blk512 >> 1;
        int mt = t / 9, k2 = t - 9 * mt;
        int oc = mt * 16 + nl, c = kb * 32 + cc;
        wt_ob[u] = (_Float16)((oc < NOFF_) ? wo[(oc * CIN_ + c) * K2_ + k2] : 0.f);
    } else if (gid < NW_B + NW_OB + NBORD) {
        int s = gid - (NW_B + NW_OB);
        int b2 = s / 12544, u = s % 12544;
        int cs = u & 7, cell = u >> 3;   // 1568 border cells per image
        int r, c;
        if (cell < 544) {                // padded rows {0,1,130,131}, all cols
            int r4 = cell / 136; c = cell % 136;
            r = (r4 < 2) ? r4 : r4 + 128;
        } else {                         // rows 2..129, cols {0,1,2,131..135}
            int c2 = cell - 544;
            r = 2 + (c2 >> 3);
            int c8 = c2 & 7;
            c = (c8 < 3) ? c8 : c8 + 128;
        }
        *(f16x8*)(hx + (((size_t)b2 * PR_ + r) * PC_ + c) * 64 + cs * 8) = splat8(0.f);
    }
}

// ---------------------------------------------------------------------------
// Fused: DMA-stage hx tile -> offset conv (f16 MFMA, dense A-frags) ->
// offsets to registers via shfl -> PRECOMPUTED sampling metadata (addrs,
// weights, validity masks for all 9 taps; 9-way ILP) -> streaming main loop
// {A-frag VMEM prefetch -> 8 ds_read -> blend -> 8 MFMA (setprio)}.
// Block = 64 px, 256 thr (4 waves), ONE barrier, 44 KiB LDS -> 3 blocks/CU.
// ---------------------------------------------------------------------------
__global__ __launch_bounds__(256, 3) void deform_all(const _Float16* __restrict__ hx,
                                                     const _Float16* __restrict__ wt_b,
                                                     const _Float16* __restrict__ wt_ob,
                                                     float* __restrict__ out) {
    __shared__ __align__(16) _Float16 xt[NSEGP * 8];   // 44 KiB

    const int tid = threadIdx.x;
    int blk = blockIdx.x;
    blk = (blk & 7) * 128 + (blk >> 3);    // XCD swizzle (1024 % 8 == 0, bijective)
    const int b   = blk >> 8;
    const int r2  = blk & 255;
    const int oh  = r2 >> 1;
    const int ow0 = (r2 & 1) << 6;

    // ---- stage x tile: global_load_lds, linear LDS dest, swizzled source ---
    const _Float16* hrow = hx + (((size_t)b * PR_ + oh) * PC_ + ow0) * 64;
    #pragma unroll
    for (int t = 0; t < NSEGP / 256; ++t) {
        int d  = t * 256 + tid;            // linear LDS 16B-seg index
        int dc = min(d, NSEG - 1);         // clamp pad lanes to a valid src
        int col = dc % TCOLS;
        int rc  = dc / TCOLS;
        int cs  = rc & 7;                  // channel octet (slot)
        int r   = rc >> 3;                 // tile row
        const _Float16* src = hrow + ((size_t)r * PC_ + col) * 64 + cs * 8;
        __builtin_amdgcn_global_load_lds(
            (const __attribute__((address_space(1))) void*)src,
            (__attribute__((address_space(3))) void*)(xt + (size_t)d * 8),
            16, 0, 0);
    }
    __syncthreads();                       // the only barrier (drains vmcnt)

    const int lane = tid & 63;
    const int cq   = tid >> 6;             // wave id -> pixel group
    const int quad = lane >> 4;            // channel octet within kb half
    const int nl   = lane & 15;
    const int pix  = cq * 16 + nl;         // this lane's pixel (B-frag column)
    const int ow   = ow0 + pix;

    const _Float16* wob_l = wt_ob + nl * 32 + quad * 8;   // dense frag base
    const _Float16* wtb_l = wt_b  + nl * 32 + quad * 8;

    // ---- offset conv via f16 MFMA: out[32 oc][16 px of this wave], K=576 ----
    f32x4 oacc[2];
    oacc[0] = (f32x4){0.f, 0.f, 0.f, 0.f};
    oacc[1] = (f32x4){0.f, 0.f, 0.f, 0.f};
    #pragma unroll
    for (int t9 = 0; t9 < 9; ++t9) {
        int ky = t9 / 3, kx = t9 - 3 * (t9 / 3);
        #pragma unroll
        for (int kb = 0; kb < 2; ++kb) {
            f16x8 bfr = *(const f16x8*)&xt[((((ky + 1) * 8) + kb * 4 + quad) * TCOLS + pix + kx + 2) * 8];
            #pragma unroll
            for (int mt = 0; mt < 2; ++mt) {
                f16x8 afr = *(const f16x8*)(wob_l + (((mt * 9 + t9) * 2 + kb) << 9));
                oacc[mt] = __builtin_amdgcn_mfma_f32_16x16x32_f16(afr, bfr, oacc[mt], 0, 0, 0);
            }
        }
    }
    // oacc[mt][r] holds offset-channel oc = mt*16 + quad*4 + r for pixel cq*16+nl.

    // ---- hoist ALL offsets for this lane's pixel into registers (18 shfl) ----
    float dyv[9], dxv[9];
    #pragma unroll
    for (int k2 = 0; k2 < 9; ++k2) {
        const int oc0 = 2 * k2;
        const int mt  = oc0 >> 4;
        const int sq  = (oc0 & 15) >> 2;
        const int r0  = oc0 & 3;
        dyv[k2] = __shfl(oacc[mt][r0],     sq * 16 + nl, 64);
        dxv[k2] = __shfl(oacc[mt][r0 + 1], sq * 16 + nl, 64);
    }

    // ---- precompute ALL sampling metadata (9-way ILP, off critical path) ----
    int   A00[9];                 // tile base address (halfs), clamped
    float Wf[9][4];               // bilinear weights (validity-zeroed)
    unsigned okm = 0, dxm = 0, dym = 0;   // per-tap flags
    #pragma unroll
    for (int k2 = 0; k2 < 9; ++k2) {
        const int ky = k2 / 3, kx = k2 - 3 * (k2 / 3);
        float py = (float)(oh - 1 + ky) + dyv[k2];
        float px = (float)(ow - 1 + kx) + dxv[k2];
        float y0f = floorf(py), x0f = floorf(px);
        float ly = py - y0f,    lx = px - x0f;
        int   y0 = (int)y0f,    x0 = (int)x0f;
        int   y1 = y0 + 1,      x1 = x0 + 1;

        float wy0 = 1.f - ly, wx0 = 1.f - lx;
        float w00 = wy0 * wx0, w01 = wy0 * lx, w10 = ly * wx0, w11 = ly * lx;

        bool vy0 = (unsigned)y0 < (unsigned)H_;
        bool vy1 = (unsigned)y1 < (unsigned)H_;
        bool vx0 = (unsigned)x0 < (unsigned)W_;
        bool vx1 = (unsigned)x1 < (unsigned)W_;
        if (!(vy0 & vx0)) w00 = 0.f;
        if (!(vy0 & vx1)) w01 = 0.f;
        if (!(vy1 & vx0)) w10 = 0.f;
        if (!(vy1 & vx1)) w11 = 0.f;
        Wf[k2][0] = w00; Wf[k2][1] = w01; Wf[k2][2] = w10; Wf[k2][3] = w11;

        int ty0 = y0 - (oh - 2), ty1 = ty0 + 1;
        int tx0 = x0 - (ow0 - 3), tx1 = tx0 + 1;
        bool i00 = (unsigned)ty0 < TROWS && (unsigned)tx0 < TCOLS;
        bool i01 = (unsigned)ty0 < TROWS && (unsigned)tx1 < TCOLS;
        bool i10 = (unsigned)ty1 < TROWS && (unsigned)tx0 < TCOLS;
        bool i11 = (unsigned)ty1 < TROWS && (unsigned)tx1 < TCOLS;
        bool ok = (w00 == 0.f || i00) && (w01 == 0.f || i01) &&
                  (w10 == 0.f || i10) && (w11 == 0.f || i11);
        if (ok) okm |= 1u << k2;

        int tyc0 = min(max(ty0, 0), TROWS - 1), tyc1 = min(max(ty1, 0), TROWS - 1);
        int txc0 = min(max(tx0, 0), TCOLS - 1), txc1 = min(max(tx1, 0), TCOLS - 1);
        if (txc1 != txc0) dxm |= 1u << k2;     // => txc1 == txc0 + 1
        if (tyc1 != tyc0) dym |= 1u << k2;     // => tyc1 == tyc0 + 1
        A00[k2] = ((tyc0 * 8 + quad) * TCOLS + txc0) * 8;
    }

    // ---- streaming main loop: prefetch A-frags -> ds_read -> blend -> MFMA --
    f32x4 acc[4];
    #pragma unroll
    for (int mb = 0; mb < 4; ++mb) acc[mb] = (f32x4){0.f, 0.f, 0.f, 0.f};

    #pragma unroll
    for (int k2 = 0; k2 < 9; ++k2) {
        // A-frag VMEM prefetch (independent of everything; hides under LDS+blend)
        f16x8 afr0[4], afr1[4];
        #pragma unroll
        for (int mb = 0; mb < 4; ++mb) {
            afr0[mb] = *(const f16x8*)(wtb_l + (((mb * 9 + k2) * 2 + 0) << 9));
            afr1[mb] = *(const f16x8*)(wtb_l + (((mb * 9 + k2) * 2 + 1) << 9));
        }

        f16x8 W00 = splat8(Wf[k2][0]), W01 = splat8(Wf[k2][1]);
        f16x8 W10 = splat8(Wf[k2][2]), W11 = splat8(Wf[k2][3]);

        f16x8 v0, v1;   // B-frags: channels quad*8.. (kb0) and 32+quad*8.. (kb1)
        if (okm & (1u << k2)) {
            const int a00 = A00[k2];
            const int a01 = a00 + (int)((dxm >> k2) & 1u) * 8;
            const int a10 = a00 + (int)((dym >> k2) & 1u) * (8 * TCOLS * 8);
            const int a11 = a10 + (a01 - a00);
            const int KB1 = 4 * TCOLS * 8;   // slot +4 => channels +32
            f16x8 c00a = *(const f16x8*)&xt[a00], c00b = *(const f16x8*)&xt[a00 + KB1];
            f16x8 c01a = *(const f16x8*)&xt[a01], c01b = *(const f16x8*)&xt[a01 + KB1];
            f16x8 c10a = *(const f16x8*)&xt[a10], c10b = *(const f16x8*)&xt[a10 + KB1];
            f16x8 c11a = *(const f16x8*)&xt[a11], c11b = *(const f16x8*)&xt[a11 + KB1];
            v0 = c00a * W00 + c01a * W01 + c10a * W10 + c11a * W11;
            v1 = c00b * W00 + c01b * W01 + c10b * W10 + c11b * W11;
        } else {
            // rare fallback: image-clamped gather from padded hx
            const int ky = k2 / 3, kx = k2 - 3 * (k2 / 3);
            float py = (float)(oh - 1 + ky) + dyv[k2];
            float px = (float)(ow - 1 + kx) + dxv[k2];
            int y0 = (int)floorf(py), x0 = (int)floorf(px);
            int y0c = min(max(y0, 0), H_ - 1), y1c = min(max(y0 + 1, 0), H_ - 1);
            int x0c = min(max(x0, 0), W_ - 1), x1c = min(max(x0 + 1, 0), W_ - 1);
            const _Float16* hb = hx + (size_t)b * PR_ * PC_ * 64 + quad * 8;
            const _Float16* g00 = hb + (((y0c + 2) * PC_) + x0c + 3) * 64;
            const _Float16* g01 = hb + (((y0c + 2) * PC_) + x1c + 3) * 64;
            const _Float16* g10 = hb + (((y1c + 2) * PC_) + x0c + 3) * 64;
            const _Float16* g11 = hb + (((y1c + 2) * PC_) + x1c + 3) * 64;
            v0 = (*(const f16x8*)g00) * W00 + (*(const f16x8*)g01) * W01 +
                 (*(const f16x8*)g10) * W10 + (*(const f16x8*)g11) * W11;
            v1 = (*(const f16x8*)(g00 + 32)) * W00 + (*(const f16x8*)(g01 + 32)) * W01 +
                 (*(const f16x8*)(g10 + 32)) * W10 + (*(const f16x8*)(g11 + 32)) * W11;
        }

        __builtin_amdgcn_s_setprio(1);
        #pragma unroll
        for (int mb = 0; mb < 4; ++mb) {
            acc[mb] = __builtin_amdgcn_mfma_f32_16x16x32_f16(afr0[mb], v0, acc[mb], 0, 0, 0);
            acc[mb] = __builtin_amdgcn_mfma_f32_16x16x32_f16(afr1[mb], v1, acc[mb], 0, 0, 0);
        }
        __builtin_amdgcn_s_setprio(0);
    }

    // epilogue: C/D col = pixel (nl), row = quad*4 + r (verified layout)
    #pragma unroll
    for (int mb = 0; mb < 4; ++mb)
        #pragma unroll
        for (int r = 0; r < 4; ++r) {
            int o = mb * 16 + quad * 4 + r;
            out[(b * COUT_ + o) * HW_ + oh * W_ + ow0 + pix] = acc[mb][r];
        }
}

// ---------------------------------------------------------------------------
extern "C" void kernel_launch(void* const* d_in, const int* in_sizes, int n_in,
                              void* d_out, int out_size, void* d_ws, size_t ws_size,
                              hipStream_t stream) {
    const float* x        = (const float*)d_in[0];  // (4, 64, 128, 128)
    const float* w_offset = (const float*)d_in[1];  // (18, 64, 3, 3)
    const float* w_deform = (const float*)d_in[2];  // (64, 64, 3, 3)
    float* out = (float*)d_out;                     // (4, 64, 128, 128)

    _Float16* hx    = (_Float16*)d_ws;                        // 4*132*136*64 halfs (9.2 MB)
    _Float16* wt_b  = hx + (size_t)B_ * PR_ * PC_ * 64;       // 36864 halfs (dense frags)
    _Float16* wt_ob = wt_b + (size_t)NW_B;                    // 18432 halfs (dense frags)

    x2h_prep<<<B_ * H_, 256, 0, stream>>>(x, w_deform, w_offset, hx, wt_b, wt_ob);
    deform_all<<<B_ * H_ * (W_ / 64), 256, 0, stream>>>(hx, wt_b, wt_ob, out);
}

// Round 10
// 107.480 us; speedup vs baseline: 1.0851x; 1.0281x over previous
//
#include <hip/hip_runtime.h>

// Problem constants
#define B_    4
#define CIN_  64
#define COUT_ 64
#define H_    128
#define W_    128
#define HW_   (H_*W_)
#define K2_   9
#define NOFF_ 18

// padded NHWC fp16 tensor: rows -2..129 (132), cols -3..132 (136), 64 ch
#define PR_   132
#define PC_   136
// x tile in LDS: rows oh-2..oh+2, cols ow0-3..ow0+66
// swizzled layout: 16B seg index d = (row*8 + slot)*TCOLS + col, slot = ch>>3
//   read bank residue = (6*slot + col) % 8, col varies per lane -> uniform
// staged with LINEAR lds dest + pre-swizzled global source (global_load_lds)
#define TROWS 5
#define TCOLS 70
#define NSEG  (TROWS * 8 * TCOLS)        // 2800 16B segments
#define NSEGP 2816                       // padded to 22*128 (pad never read)

typedef _Float16 f16x8 __attribute__((ext_vector_type(8)));  // MFMA A/B frag
typedef float    f32x4 __attribute__((ext_vector_type(4)));  // MFMA C/D

__device__ __forceinline__ f16x8 splat8(float f) {
    _Float16 h = (_Float16)f;
    return (f16x8){h, h, h, h, h, h, h, h};
}
__device__ __forceinline__ f16x8 splat8h(_Float16 h) {
    return (f16x8){h, h, h, h, h, h, h, h};
}
__device__ __forceinline__ _Float16 lo16(unsigned u) {
    return __builtin_bit_cast(_Float16, (unsigned short)(u & 0xffffu));
}
__device__ __forceinline__ _Float16 hi16(unsigned u) {
    return __builtin_bit_cast(_Float16, (unsigned short)(u >> 16));
}

// ---------------------------------------------------------------------------
// x (NCHW fp32) -> hx interior (padded NHWC fp16), fused with:
//   - DENSE fp16 weight repack: one MFMA A-frag = one contiguous 1KB block
//       wt_b [((mb*9+k2)*2+kb)*512 + nl*32 + cc] = wd[o=mb*16+nl][c=kb*32+cc][k2]
//       wt_ob same with mt in 0..1 (rows 18..31 zero)
//   - border-only zero of hx (interior fully overwritten here)
// Block = (b, y) row; thread = (xpos, c-half). 512 blocks x 256 thr.
// ---------------------------------------------------------------------------
#define NW_B   (COUT_ * 576)                 // 36864 wt_b halfs
#define NW_OB  (32 * 576)                    // 18432 wt_ob halfs
#define NBORD  (4 * 12544)                   // 50176 border 16B segments
__global__ __launch_bounds__(256) void x2h_prep(const float* __restrict__ x,
                                                const float* __restrict__ wd,
                                                const float* __restrict__ wo,
                                                _Float16* __restrict__ hx,
                                                _Float16* __restrict__ wt_b,
                                                _Float16* __restrict__ wt_ob) {
    const int blk = blockIdx.x;          // b*128 + y
    const int b = blk >> 7, y = blk & 127;
    const int xp = threadIdx.x & 127;
    const int ch = threadIdx.x >> 7;     // 0/1 -> channels 0-31 / 32-63
    const float* xs = x + ((b * CIN_ + ch * 32) * H_ + y) * W_ + xp;
    _Float16* hd = hx + (((size_t)b * PR_ + y + 2) * PC_ + xp + 3) * 64 + ch * 32;

    f16x8 h[4];
    #pragma unroll
    for (int j = 0; j < 4; ++j)
        #pragma unroll
        for (int t = 0; t < 8; ++t)
            h[j][t] = (_Float16)xs[(j * 8 + t) * HW_];
    #pragma unroll
    for (int j = 0; j < 4; ++j)
        *(f16x8*)(hd + j * 8) = h[j];

    // ---- side tasks: weight repack + border zeroing (one task per thread) --
    const int gid = blk * 256 + threadIdx.x;
    if (gid < NW_B) {
        int blk512 = gid >> 9, w = gid & 511;
        int nl = w >> 5, cc = w & 31;
        int kb = blk512 & 1, t = blk512 >> 1;
        int mb = t / 9, k2 = t - 9 * mb;
        int o = mb * 16 + nl, c = kb * 32 + cc;
        wt_b[gid] = (_Float16)wd[(o * CIN_ + c) * K2_ + k2];
    } else if (gid < NW_B + NW_OB) {
        int u = gid - NW_B;
        int blk512 = u >> 9, w = u & 511;
        int nl = w >> 5, cc = w & 31;
        int kb = blk512 & 1, t = blk512 >> 1;
        int mt = t / 9, k2 = t - 9 * mt;
        int oc = mt * 16 + nl, c = kb * 32 + cc;
        wt_ob[u] = (_Float16)((oc < NOFF_) ? wo[(oc * CIN_ + c) * K2_ + k2] : 0.f);
    } else if (gid < NW_B + NW_OB + NBORD) {
        int s = gid - (NW_B + NW_OB);
        int b2 = s / 12544, u = s % 12544;
        int cs = u & 7, cell = u >> 3;   // 1568 border cells per image
        int r, c;
        if (cell < 544) {                // padded rows {0,1,130,131}, all cols
            int r4 = cell / 136; c = cell % 136;
            r = (r4 < 2) ? r4 : r4 + 128;
        } else {                         // rows 2..129, cols {0,1,2,131..135}
            int c2 = cell - 544;
            r = 2 + (c2 >> 3);
            int c8 = c2 & 7;
            c = (c8 < 3) ? c8 : c8 + 128;
        }
        *(f16x8*)(hx + (((size_t)b2 * PR_ + r) * PC_ + c) * 64 + cs * 8) = splat8(0.f);
    }
}

// ---------------------------------------------------------------------------
// Fused, DUAL-PIXEL-GROUP waves: each wave owns 32 px (two 16-px B-frag
// groups) and loads every weight A-frag ONCE, feeding 2 MFMAs -> weight VMEM
// per block halves (432->216 KB). Block = 64 px, 128 thr (2 waves), same
// 44 KiB tile -> 3 blocks/CU; TLP->ILP swap (2 independent pg chains/wave).
// Round-4 skeleton otherwise: DMA stage -> oconv -> shfl -> packed metadata
// (round-7 verified forms) -> streaming loop w/ straight-line clamped loads
// + rare fixup + setprio MFMA clusters.
// ---------------------------------------------------------------------------
__global__ __launch_bounds__(128, 2) void deform_all(const _Float16* __restrict__ hx,
                                                     const _Float16* __restrict__ wt_b,
                                                     const _Float16* __restrict__ wt_ob,
                                                     float* __restrict__ out) {
    __shared__ __align__(16) _Float16 xt[NSEGP * 8];   // 44 KiB

    const int tid = threadIdx.x;
    int blk = blockIdx.x;
    blk = (blk & 7) * 128 + (blk >> 3);    // XCD swizzle (1024 % 8 == 0, bijective)
    const int b   = blk >> 8;
    const int r2  = blk & 255;
    const int oh  = r2 >> 1;
    const int ow0 = (r2 & 1) << 6;

    // ---- stage x tile: global_load_lds, linear LDS dest, swizzled source ---
    const _Float16* hrow = hx + (((size_t)b * PR_ + oh) * PC_ + ow0) * 64;
    #pragma unroll
    for (int t = 0; t < NSEGP / 128; ++t) {
        int d  = t * 128 + tid;            // linear LDS 16B-seg index
        int dc = min(d, NSEG - 1);         // clamp pad lanes to a valid src
        int col = dc % TCOLS;
        int rc  = dc / TCOLS;
        int cs  = rc & 7;                  // channel octet (slot)
        int r   = rc >> 3;                 // tile row
        const _Float16* src = hrow + ((size_t)r * PC_ + col) * 64 + cs * 8;
        __builtin_amdgcn_global_load_lds(
            (const __attribute__((address_space(1))) void*)src,
            (__attribute__((address_space(3))) void*)(xt + (size_t)d * 8),
            16, 0, 0);
    }
    __syncthreads();                       // the only barrier (drains vmcnt)

    const int lane = tid & 63;
    const int cq   = tid >> 6;             // wave id 0..1 -> 32-px group
    const int quad = lane >> 4;            // channel octet within kb half
    const int nl   = lane & 15;

    const _Float16* wob_l = wt_ob + nl * 32 + quad * 8;   // dense frag base
    const _Float16* wtb_l = wt_b  + nl * 32 + quad * 8;
    const _Float16* hb    = hx + (size_t)b * (PR_ * PC_ * 64);

    // pixel for (pg, lane): pix = cq*32 + pg*16 + nl
    // ---- offset conv: out[32 oc][16 px] per pg; A-frags loaded once ------
    f32x4 oacc[2][2];                      // [mt][pg]
    #pragma unroll
    for (int mt = 0; mt < 2; ++mt)
        #pragma unroll
        for (int pg = 0; pg < 2; ++pg)
            oacc[mt][pg] = (f32x4){0.f, 0.f, 0.f, 0.f};
    #pragma unroll
    for (int t9 = 0; t9 < 9; ++t9) {
        int ky = t9 / 3, kx = t9 - 3 * (t9 / 3);
        #pragma unroll
        for (int kb = 0; kb < 2; ++kb) {
            f16x8 afr[2];
            #pragma unroll
            for (int mt = 0; mt < 2; ++mt)
                afr[mt] = *(const f16x8*)(wob_l + (((mt * 9 + t9) * 2 + kb) << 9));
            #pragma unroll
            for (int pg = 0; pg < 2; ++pg) {
                const int pix = cq * 32 + pg * 16 + nl;
                f16x8 bfr = *(const f16x8*)&xt[((((ky + 1) * 8) + kb * 4 + quad) * TCOLS + pix + kx + 2) * 8];
                #pragma unroll
                for (int mt = 0; mt < 2; ++mt)
                    oacc[mt][pg] = __builtin_amdgcn_mfma_f32_16x16x32_f16(afr[mt], bfr, oacc[mt][pg], 0, 0, 0);
            }
        }
    }
    // oacc[mt][pg][r] holds oc = mt*16 + quad*4 + r for pixel cq*32+pg*16+nl.

    // ---- hoist offsets (36 shfl) + packed metadata per pg ------------------
    int      A00[2][9];
    unsigned Wp[2][9][2];         // f16-packed bilinear weights (round-7 form)
    int      P0[2][9];            // (y0 & 0xffff) | (x0 << 16)
    unsigned okm[2] = {0, 0}, dxm[2] = {0, 0}, dym[2] = {0, 0};
    #pragma unroll
    for (int pg = 0; pg < 2; ++pg) {
        const int ow = ow0 + cq * 32 + pg * 16 + nl;
        #pragma unroll
        for (int k2 = 0; k2 < 9; ++k2) {
            const int oc0 = 2 * k2;
            const int mt  = oc0 >> 4;
            const int sq  = (oc0 & 15) >> 2;
            const int r0  = oc0 & 3;
            float dy = __shfl(oacc[mt][pg][r0],     sq * 16 + nl, 64);
            float dx = __shfl(oacc[mt][pg][r0 + 1], sq * 16 + nl, 64);

            const int ky = k2 / 3, kx = k2 - 3 * (k2 / 3);
            float py = (float)(oh - 1 + ky) + dy;
            float px = (float)(ow - 1 + kx) + dx;
            float y0f = floorf(py), x0f = floorf(px);
            float ly = py - y0f,    lx = px - x0f;
            int   y0 = (int)y0f,    x0 = (int)x0f;
            int   y1 = y0 + 1,      x1 = x0 + 1;

            float wy0 = 1.f - ly, wx0 = 1.f - lx;
            float w00 = wy0 * wx0, w01 = wy0 * lx, w10 = ly * wx0, w11 = ly * lx;

            bool vy0 = (unsigned)y0 < (unsigned)H_;
            bool vy1 = (unsigned)y1 < (unsigned)H_;
            bool vx0 = (unsigned)x0 < (unsigned)W_;
            bool vx1 = (unsigned)x1 < (unsigned)W_;
            if (!(vy0 & vx0)) w00 = 0.f;
            if (!(vy0 & vx1)) w01 = 0.f;
            if (!(vy1 & vx0)) w10 = 0.f;
            if (!(vy1 & vx1)) w11 = 0.f;
            unsigned h00 = (unsigned)__builtin_bit_cast(unsigned short, (_Float16)w00);
            unsigned h01 = (unsigned)__builtin_bit_cast(unsigned short, (_Float16)w01);
            unsigned h10 = (unsigned)__builtin_bit_cast(unsigned short, (_Float16)w10);
            unsigned h11 = (unsigned)__builtin_bit_cast(unsigned short, (_Float16)w11);
            Wp[pg][k2][0] = h00 | (h01 << 16);
            Wp[pg][k2][1] = h10 | (h11 << 16);
            P0[pg][k2] = (y0 & 0xffff) | (x0 << 16);

            int ty0 = y0 - (oh - 2), ty1 = ty0 + 1;
            int tx0 = x0 - (ow0 - 3), tx1 = tx0 + 1;
            bool i00 = (unsigned)ty0 < TROWS && (unsigned)tx0 < TCOLS;
            bool i01 = (unsigned)ty0 < TROWS && (unsigned)tx1 < TCOLS;
            bool i10 = (unsigned)ty1 < TROWS && (unsigned)tx0 < TCOLS;
            bool i11 = (unsigned)ty1 < TROWS && (unsigned)tx1 < TCOLS;
            bool ok = (w00 == 0.f || i00) && (w01 == 0.f || i01) &&
                      (w10 == 0.f || i10) && (w11 == 0.f || i11);
            if (ok) okm[pg] |= 1u << k2;

            int tyc0 = min(max(ty0, 0), TROWS - 1), tyc1 = min(max(ty1, 0), TROWS - 1);
            int txc0 = min(max(tx0, 0), TCOLS - 1), txc1 = min(max(tx1, 0), TCOLS - 1);
            if (txc1 != txc0) dxm[pg] |= 1u << k2;     // => txc1 == txc0 + 1
            if (tyc1 != tyc0) dym[pg] |= 1u << k2;     // => tyc1 == tyc0 + 1
            A00[pg][k2] = ((tyc0 * 8 + quad) * TCOLS + txc0) * 8;
        }
    }

    // ---- main loop: A-frags loaded once, consumed by BOTH pixel groups ----
    f32x4 acc[2][4];                       // [pg][mb]
    #pragma unroll
    for (int pg = 0; pg < 2; ++pg)
        #pragma unroll
        for (int mb = 0; mb < 4; ++mb) acc[pg][mb] = (f32x4){0.f, 0.f, 0.f, 0.f};

    const int KB1 = 4 * TCOLS * 8;         // slot +4 => channels +32

    #pragma unroll
    for (int k2 = 0; k2 < 9; ++k2) {
        // A-frag VMEM loads (ONE load, TWO consumers -> halved weight traffic)
        f16x8 af0[4], af1[4];
        #pragma unroll
        for (int mb = 0; mb < 4; ++mb) {
            af0[mb] = *(const f16x8*)(wtb_l + (((mb * 9 + k2) * 2 + 0) << 9));
            af1[mb] = *(const f16x8*)(wtb_l + (((mb * 9 + k2) * 2 + 1) << 9));
        }

        #pragma unroll
        for (int pg = 0; pg < 2; ++pg) {
            // unconditional clamped corner loads (always in-tile addresses)
            const int a00 = A00[pg][k2];
            const int a01 = a00 + (int)((dxm[pg] >> k2) & 1u) * 8;
            const int a10 = a00 + (int)((dym[pg] >> k2) & 1u) * (8 * TCOLS * 8);
            const int a11 = a10 + (a01 - a00);
            f16x8 c00a = *(const f16x8*)&xt[a00], c00b = *(const f16x8*)&xt[a00 + KB1];
            f16x8 c01a = *(const f16x8*)&xt[a01], c01b = *(const f16x8*)&xt[a01 + KB1];
            f16x8 c10a = *(const f16x8*)&xt[a10], c10b = *(const f16x8*)&xt[a10 + KB1];
            f16x8 c11a = *(const f16x8*)&xt[a11], c11b = *(const f16x8*)&xt[a11 + KB1];

            f16x8 W00 = splat8h(lo16(Wp[pg][k2][0])), W01 = splat8h(hi16(Wp[pg][k2][0]));
            f16x8 W10 = splat8h(lo16(Wp[pg][k2][1])), W11 = splat8h(hi16(Wp[pg][k2][1]));

            f16x8 v0 = c00a * W00 + c01a * W01 + c10a * W10 + c11a * W11;
            f16x8 v1 = c00b * W00 + c01b * W01 + c10b * W10 + c11b * W11;

            if (!((okm[pg] >> k2) & 1u)) {
                // rare fixup: image-clamped gather from padded hx
                int pk = P0[pg][k2];
                int y0 = (pk << 16) >> 16;      // sext low16
                int x0 = pk >> 16;
                int y0c = min(max(y0, 0), H_ - 1), y1c = min(max(y0 + 1, 0), H_ - 1);
                int x0c = min(max(x0, 0), W_ - 1), x1c = min(max(x0 + 1, 0), W_ - 1);
                const _Float16* hg = hb + quad * 8;
                const _Float16* g00 = hg + (((y0c + 2) * PC_) + x0c + 3) * 64;
                const _Float16* g01 = hg + (((y0c + 2) * PC_) + x1c + 3) * 64;
                const _Float16* g10 = hg + (((y1c + 2) * PC_) + x0c + 3) * 64;
                const _Float16* g11 = hg + (((y1c + 2) * PC_) + x1c + 3) * 64;
                v0 = (*(const f16x8*)g00) * W00 + (*(const f16x8*)g01) * W01 +
                     (*(const f16x8*)g10) * W10 + (*(const f16x8*)g11) * W11;
                v1 = (*(const f16x8*)(g00 + 32)) * W00 + (*(const f16x8*)(g01 + 32)) * W01 +
                     (*(const f16x8*)(g10 + 32)) * W10 + (*(const f16x8*)(g11 + 32)) * W11;
            }

            __builtin_amdgcn_s_setprio(1);
            #pragma unroll
            for (int mb = 0; mb < 4; ++mb) {
                acc[pg][mb] = __builtin_amdgcn_mfma_f32_16x16x32_f16(af0[mb], v0, acc[pg][mb], 0, 0, 0);
                acc[pg][mb] = __builtin_amdgcn_mfma_f32_16x16x32_f16(af1[mb], v1, acc[pg][mb], 0, 0, 0);
            }
            __builtin_amdgcn_s_setprio(0);
        }
    }

    // epilogue: C/D col = pixel (nl), row = quad*4 + r (verified layout)
    #pragma unroll
    for (int pg = 0; pg < 2; ++pg)
        #pragma unroll
        for (int mb = 0; mb < 4; ++mb)
            #pragma unroll
            for (int r = 0; r < 4; ++r) {
                int o = mb * 16 + quad * 4 + r;
                out[(b * COUT_ + o) * HW_ + oh * W_ + ow0 + cq * 32 + pg * 16 + nl] = acc[pg][mb][r];
            }
}

// ---------------------------------------------------------------------------
extern "C" void kernel_launch(void* const* d_in, const int* in_sizes, int n_in,
                              void* d_out, int out_size, void* d_ws, size_t ws_size,
                              hipStream_t stream) {
    const float* x        = (const float*)d_in[0];  // (4, 64, 128, 128)
    const float* w_offset = (const float*)d_in[1];  // (18, 64, 3, 3)
    const float* w_deform = (const float*)d_in[2];  // (64, 64, 3, 3)
    float* out = (float*)d_out;                     // (4, 64, 128, 128)

    _Float16* hx    = (_Float16*)d_ws;                        // 4*132*136*64 halfs (9.2 MB)
    _Float16* wt_b  = hx + (size_t)B_ * PR_ * PC_ * 64;       // 36864 halfs (dense frags)
    _Float16* wt_ob = wt_b + (size_t)NW_B;                    // 18432 halfs (dense frags)

    x2h_prep<<<B_ * H_, 256, 0, stream>>>(x, w_deform, w_offset, hx, wt_b, wt_ob);
    deform_all<<<B_ * H_ * (W_ / 64), 128, 0, stream>>>(hx, wt_b, wt_ob, out);
}